// Round 7
// baseline (222.901 us; speedup 1.0000x reference)
//
#include <hip/hip_runtime.h>

// HierarchicalClassifier: B=16384, D=2048, N_TOP=8, N_CLASS=16
// out[b, t*16+c] = sigmoid(f.top_W[t]+top_b[t]) * softmax_c(f.bottom_W[t,:,c]+bot_b[t,c])
//
// R13: round-count collapse. Ledger: R7/R9/R10 (schedule forcing) no effect;
// R12 (2.6x TCP-byte cut) no effect — both measured kernels 78.8/79.3us with
// MfmaUtil ~4.4%, VALUBusy ~3.4%, i.e. ~95% idle; no throughput model reaches
// 79us. Shared structure of all losers: 16-32 serialized dependency rounds
// (wait->barrier->issue), each an effective ~2.5-6k cycles (full-drain rounds
// x DVFS-depressed clock on a near-idle kernel). Lever: cut ROUNDS.
// Structure: split-K 4-way, two kernels.
//   hc_main: 512 blocks (= 128 rowgroups x 4 K-quarters, kq-major so the 4
//   siblings of a rowgroup share an XCD: bids differ by 128 = 0 mod 8),
//   256 thr, 2 blocks/CU (LDS 72KB). Block: 128 rows x K=512 in FOUR steps
//   of K-chunk 128: {stage-next 36KB B -> LDS dbuf (global_load_lds w16,
//   9 rounds), 16 f32x4 A-loads/wave, 72 MFMA/wave, one barrier}. Partials
//   (f32, 4x16384x144 = 37.7MB) to workspace.
//   hc_epi: 131072 threads: sum 4 partials + bias, sigmoid/softmax, write out.
// Compiler-managed waits (R6 lesson: compiler-scheduled was best); only 4
// rounds so even full drains are ~10k cy, covered by the co-resident block.

#define D_DIM 2048
#define NTILE 9             // 144 columns / 16
#define CH_B 36864          // one K-chunk of B: 128k x 144 cols fp16 = 36KB
#define NCHUNK 16           // 2048 / 128

using f32x4 = float __attribute__((ext_vector_type(4)));
using half8 = _Float16 __attribute__((ext_vector_type(8)));
using fp16x2 = __fp16 __attribute__((ext_vector_type(2)));

// B layout (halfs): S[((chunk*4 + kf)*9 + nt)*512 + lane*8 + j]
//   = W[n = nt*16 + (lane&15)][k = chunk*128 + kf*32 + (lane>>4)*8 + j]
// W rows 0..7 = top_W, 8..135 = bottom_W[t][:,c] (n-8 = t*16+c), 136..143 = 0.
// This is exactly the LDS image: chunk c staged linearly -> frag (kf,nt) at
// byte offset kf*9216 + nt*1024 + lane*16.
__global__ void prep_weights(const float* __restrict__ topW,
                             const float* __restrict__ botW,
                             _Float16* __restrict__ S) {
    int idx = blockIdx.x * blockDim.x + threadIdx.x;   // [0, 16*4*9*64)
    if (idx >= NCHUNK * 4 * NTILE * 64) return;
    int lane = idx & 63;
    int t1   = idx >> 6;          // (chunk*4 + kf)*9 + nt
    int nt   = t1 % NTILE;
    int t2   = t1 / NTILE;        // chunk*4 + kf
    int kf   = t2 & 3;
    int chunk= t2 >> 2;
    int n     = nt * 16 + (lane & 15);
    int kbase = chunk * 128 + kf * 32 + (lane >> 4) * 8;

    _Float16 v[8];
    #pragma unroll
    for (int j = 0; j < 8; j++) {
        int k = kbase + j;
        float x = 0.0f;
        if (n < 8) {
            x = topW[n * D_DIM + k];
        } else if (n < 136) {
            int t = (n - 8) >> 4, c = (n - 8) & 15;
            x = botW[(t * D_DIM + k) * 16 + c];
        }
        v[j] = (_Float16)x;
    }
    *(half8*)(S + (size_t)idx * 8) = *(half8*)v;
}

static __device__ __forceinline__ half8 pack_af(f32x4 a, f32x4 b) {
    fp16x2 p0 = __builtin_amdgcn_cvt_pkrtz(a[0], a[1]);
    fp16x2 p1 = __builtin_amdgcn_cvt_pkrtz(a[2], a[3]);
    fp16x2 p2 = __builtin_amdgcn_cvt_pkrtz(b[0], b[1]);
    fp16x2 p3 = __builtin_amdgcn_cvt_pkrtz(b[2], b[3]);
    half8 r;
    r[0] = (_Float16)p0[0]; r[1] = (_Float16)p0[1];
    r[2] = (_Float16)p1[0]; r[3] = (_Float16)p1[1];
    r[4] = (_Float16)p2[0]; r[5] = (_Float16)p2[1];
    r[6] = (_Float16)p3[0]; r[7] = (_Float16)p3[1];
    return r;
}

typedef __attribute__((address_space(1))) const void gv_t;
typedef __attribute__((address_space(3))) void lv_t;

// Main GEMM: block (rg, kq) computes partial P[kq][rg*128..+128)[0..144) over
// k in [kq*512, +512). Waves each own 32 rows (2 row-frags of 16).
__global__ __launch_bounds__(256, 2) void hc_main(
        const float* __restrict__ feat, const _Float16* __restrict__ S,
        float* __restrict__ P) {
    __shared__ _Float16 buf[2][CH_B / 2];   // 72 KB double buffer

    const int tid  = threadIdx.x;
    const int lane = tid & 63, wave = tid >> 6;
    const int quad = lane >> 4, low = lane & 15;
    const int rg = blockIdx.x & 127, kq = blockIdx.x >> 7;   // kq-major
    const int row0 = rg * 128 + wave * 32;

    const char* gB = (const char*)S + (size_t)(kq * 4) * CH_B;
    const char* lB = (const char*)&buf[0][0];

    // A: lane (low,quad) reads feat[row0 + low (+16)][kq*512 + s*128 + kf*32 + quad*8 + j]
    const float* Ar = feat + (size_t)(row0 + low) * D_DIM + kq * 512 + quad * 8;

    f32x4 acc0[NTILE], acc1[NTILE];
    #pragma unroll
    for (int i = 0; i < NTILE; i++) { acc0[i] = (f32x4)0.0f; acc1[i] = (f32x4)0.0f; }

    // Stage chunk CH of B into buf[SLOT]: 36KB linear, 9 rounds of
    // (256 thr x 16B). LDS dest per wave-instr is wave-uniform; HW adds lane*16.
#define STAGE(SLOT, CH) do {                                               \
        const char* g_ = gB + (CH) * CH_B + (unsigned)(tid * 16);          \
        _Pragma("unroll")                                                  \
        for (int r_ = 0; r_ < 9; r_++) {                                   \
            __builtin_amdgcn_global_load_lds(                              \
                (gv_t*)(g_ + r_ * 4096),                                   \
                (lv_t*)(lB + (SLOT) * CH_B + wave * 1024 + r_ * 4096),     \
                16, 0, 0);                                                 \
        }                                                                  \
    } while (0)

    // One K-chunk (128) from buf[S_&1]: 16 A-loads, 8 packs, 36 ds_reads, 72 MFMA.
#define STEPBODY(S_) do {                                                  \
        const float* a_ = Ar + (S_) * 128;                                 \
        f32x4 aA[4], aB[4], aC[4], aD[4];                                  \
        _Pragma("unroll")                                                  \
        for (int kf = 0; kf < 4; kf++) {                                   \
            aA[kf] = *(const f32x4*)(a_ + kf * 32);                        \
            aB[kf] = *(const f32x4*)(a_ + kf * 32 + 4);                    \
            aC[kf] = *(const f32x4*)(a_ + 16 * D_DIM + kf * 32);           \
            aD[kf] = *(const f32x4*)(a_ + 16 * D_DIM + kf * 32 + 4);       \
        }                                                                  \
        _Pragma("unroll")                                                  \
        for (int kf = 0; kf < 4; kf++) {                                   \
            const half8 af0 = pack_af(aA[kf], aB[kf]);                     \
            const half8 af1 = pack_af(aC[kf], aD[kf]);                     \
            const _Float16* Lp = (const _Float16*)(lB + ((S_) & 1) * CH_B) \
                                 + kf * 4608 + lane * 8;                   \
            _Pragma("unroll")                                              \
            for (int nt = 0; nt < NTILE; nt++) {                           \
                half8 bf = *(const half8*)(Lp + nt * 512);                 \
                acc0[nt] = __builtin_amdgcn_mfma_f32_16x16x32_f16(         \
                               af0, bf, acc0[nt], 0, 0, 0);                \
                acc1[nt] = __builtin_amdgcn_mfma_f32_16x16x32_f16(         \
                               af1, bf, acc1[nt], 0, 0, 0);                \
            }                                                              \
        }                                                                  \
    } while (0)

    STAGE(0, 0); __syncthreads();
    STAGE(1, 1); STEPBODY(0); __syncthreads();
    STAGE(0, 2); STEPBODY(1); __syncthreads();
    STAGE(1, 3); STEPBODY(2); __syncthreads();
    STEPBODY(3);

#undef STAGE
#undef STEPBODY

    // Partial store. C/D layout (m89/m91): col = lane&15, row = quad*4 + reg.
    float* Pp = P + ((size_t)kq * 16384 + row0) * 144;
    #pragma unroll
    for (int nt = 0; nt < NTILE; nt++) {
        #pragma unroll
        for (int r = 0; r < 4; r++) {
            Pp[(quad * 4 + r) * 144 + nt * 16 + low]        = acc0[nt][r];
            Pp[(16 + quad * 4 + r) * 144 + nt * 16 + low]   = acc1[nt][r];
        }
    }
}

// Epilogue: thread -> (row = gt>>3, top = gt&7). Sum 4 partials + bias,
// sigmoid gate, softmax over 16, write 64B.
__global__ __launch_bounds__(256) void hc_epi(
        const float* __restrict__ P, const float* __restrict__ top_b,
        const float* __restrict__ bot_b, float* __restrict__ out) {
    const int gt  = blockIdx.x * 256 + threadIdx.x;   // [0, 131072)
    const int row = gt >> 3;
    const int top = gt & 7;
    const size_t KQS = (size_t)16384 * 144;
    const float* p0 = P + (size_t)row * 144;

    float zt = top_b[top] + p0[top] + p0[KQS + top]
             + p0[2 * KQS + top] + p0[3 * KQS + top];
    const float sig = 1.0f / (1.0f + __expf(-zt));

    const int cb = 8 + top * 16;
    f32x4 zv[4];
    #pragma unroll
    for (int i = 0; i < 4; i++) zv[i] = *(const f32x4*)(bot_b + top * 16 + i * 4);
    #pragma unroll
    for (int q = 0; q < 4; q++) {
        const float* pq = p0 + q * KQS + cb;
        #pragma unroll
        for (int i = 0; i < 4; i++) zv[i] += *(const f32x4*)(pq + i * 4);
    }

    float zmax = -1e30f;
    #pragma unroll
    for (int i = 0; i < 4; i++)
        #pragma unroll
        for (int j = 0; j < 4; j++) zmax = fmaxf(zmax, zv[i][j]);

    float s = 0.0f;
    #pragma unroll
    for (int i = 0; i < 4; i++)
        #pragma unroll
        for (int j = 0; j < 4; j++) { zv[i][j] = __expf(zv[i][j] - zmax); s += zv[i][j]; }
    const float scale = sig / s;

    float* o = out + (size_t)row * 128 + top * 16;
    #pragma unroll
    for (int i = 0; i < 4; i++) {
        f32x4 v = { zv[i][0] * scale, zv[i][1] * scale,
                    zv[i][2] * scale, zv[i][3] * scale };
        *(f32x4*)(o + i * 4) = v;
    }
}

extern "C" void kernel_launch(void* const* d_in, const int* in_sizes, int n_in,
                              void* d_out, int out_size, void* d_ws, size_t ws_size,
                              hipStream_t stream) {
    const float* feat  = (const float*)d_in[0];   // (16384, 2048)
    const float* topW  = (const float*)d_in[1];   // (8, 2048)
    const float* topB  = (const float*)d_in[2];   // (8,)
    const float* botW  = (const float*)d_in[3];   // (8, 2048, 16)
    const float* botB  = (const float*)d_in[4];   // (8, 16)
    float* out = (float*)d_out;                   // (16384, 128)

    _Float16* Bsw = (_Float16*)d_ws;                          // 576 KB swizzled B
    float* P = (float*)((char*)d_ws + (1 << 20));             // 4x16384x144 f32 = 37.7 MB

    prep_weights<<<(NCHUNK * 4 * NTILE * 64 + 255) / 256, 256, 0, stream>>>(topW, botW, Bsw);
    hc_main<<<512, 256, 0, stream>>>(feat, Bsw, P);
    hc_epi<<<512, 256, 0, stream>>>(P, topB, botB, out);
}

// Round 8
// 214.433 us; speedup vs baseline: 1.0395x; 1.0395x over previous
//
#include <hip/hip_runtime.h>

// HierarchicalClassifier: B=16384, D=2048, N_TOP=8, N_CLASS=16
// out[b, t*16+c] = sigmoid(f.top_W[t]+top_b[t]) * softmax_c(f.bottom_W[t,:,c]+bot_b[t,c])
//
// R14 = R6 (best measured: 205.6us prev session / 210.4 this session) + nt
// cache hints. Unified model fitted over R6-R13: time ~ max(total vector-mem
// bytes / ~7TB/s chip-wide L3/fabric service, latency floor). R6 sits exactly
// on the bandwidth branch (429MB / 6.9TB/s = 62us): its B re-reads (576KB x
// 64 blocks/XCD) miss L2 to L3 because A's 17MB/XCD stream thrashes the 4MB
// L2 (hence R8's L3-residency invariance — the L3/fabric path chokes either
// way). All restructures either re-added bytes (R13 split-K partials) or went
// latency-bound (R11/R12). Fix while keeping R6's proven structure: mark A
// loads + C stores NON-TEMPORAL (MUBUF nt, evict-first) so B stays L2-resident
// -> B's 295MB at L2 rate (~8.5us, overlapped), L3/fabric carries only A's
// 134MB (~21us). Numerics bit-identical to R6.

#define D_DIM 2048
#define NTILE 9          // 144 columns / 16
#define M_ROWS 32        // rows per workgroup (2 row-tiles of 16)

using f32x4 = float __attribute__((ext_vector_type(4)));
using half8 = _Float16 __attribute__((ext_vector_type(8)));
using fp16x2 = __fp16 __attribute__((ext_vector_type(2)));

// Swizzled B layout: S[(((w*16 + ks)*9 + nt)*64 + lane)*8 + j]
//   = W[n = nt*16 + (lane&15)][k = w*512 + ks*32 + (lane>>4)*8 + j]
// W rows 0..7 = top_W, 8..135 = bottom_W[t][:,c] (n-8 = t*16+c), 136..143 = 0.
__global__ void prep_weights(const float* __restrict__ topW,
                             const float* __restrict__ botW,
                             _Float16* __restrict__ S) {
    int idx = blockIdx.x * blockDim.x + threadIdx.x;   // [0, 4*16*9*64)
    if (idx >= 4 * 16 * NTILE * 64) return;
    int lane = idx & 63;
    int tmp  = idx >> 6;          // (w*16+ks)*9 + nt
    int nt   = tmp % NTILE;
    int wks  = tmp / NTILE;       // w*16+ks in [0,64)
    int n     = nt * 16 + (lane & 15);
    int kbase = wks * 32 + (lane >> 4) * 8;

    _Float16 v[8];
    #pragma unroll
    for (int j = 0; j < 8; j++) {
        int k = kbase + j;
        float x = 0.0f;
        if (n < 8) {
            x = topW[n * D_DIM + k];
        } else if (n < 136) {
            int t = (n - 8) >> 4, c = (n - 8) & 15;
            x = botW[(t * D_DIM + k) * 16 + c];
        }
        v[j] = (_Float16)x;
    }
    *(half8*)(S + (size_t)idx * 8) = *(half8*)v;
}

static __device__ __forceinline__ half8 pack_af(f32x4 a, f32x4 b) {
    fp16x2 p0 = __builtin_amdgcn_cvt_pkrtz(a[0], a[1]);
    fp16x2 p1 = __builtin_amdgcn_cvt_pkrtz(a[2], a[3]);
    fp16x2 p2 = __builtin_amdgcn_cvt_pkrtz(b[0], b[1]);
    fp16x2 p3 = __builtin_amdgcn_cvt_pkrtz(b[2], b[3]);
    half8 r;
    r[0] = (_Float16)p0[0]; r[1] = (_Float16)p0[1];
    r[2] = (_Float16)p1[0]; r[3] = (_Float16)p1[1];
    r[4] = (_Float16)p2[0]; r[5] = (_Float16)p2[1];
    r[6] = (_Float16)p3[0]; r[7] = (_Float16)p3[1];
    return r;
}

// A is streamed once (never re-read): non-temporal load keeps it evict-first
// in L2 so the shared B tile stays resident.
static __device__ __forceinline__ f32x4 ldnt(const float* p) {
    return __builtin_nontemporal_load((const f32x4*)p);
}

__global__ __launch_bounds__(256, 2) void hc_fused(
        const float* __restrict__ feat, const _Float16* __restrict__ Bsw,
        const float* __restrict__ top_b, const float* __restrict__ bot_b,
        float* __restrict__ out) {
    __shared__ float red[4][M_ROWS][148];   // [wave][row][ncol(+pad)] = 74 KB

    const int tid  = threadIdx.x;
    const int lane = tid & 63, wave = tid >> 6;
    const int quad = lane >> 4, low = lane & 15;
    const size_t row0 = (size_t)blockIdx.x * M_ROWS;

    // A: lane holds A[m=low][k = quad*8 + j]; this wave's K range = [wave*512, +512)
    const float* A0 = feat + (row0 + low) * D_DIM + wave * 512 + quad * 8;
    const float* A1 = A0 + 16 * D_DIM;
    // B: swizzled fragment stream; per (ks,nt) a contiguous 1KB wave read.
    const _Float16* Bp = Bsw + (size_t)wave * (16 * NTILE * 512) + lane * 8;

    f32x4 acc0[NTILE], acc1[NTILE];
    #pragma unroll
    for (int i = 0; i < NTILE; i++) { acc0[i] = (f32x4)0.0f; acc1[i] = (f32x4)0.0f; }

    // --- software pipeline: two named register buffer sets (SROA-safe) ---
    half8 bB0[NTILE], bB1[NTILE];
    f32x4 bA0[4], bA1[4];

    #pragma unroll
    for (int nt = 0; nt < NTILE; nt++) bB0[nt] = *(const half8*)(Bp + nt * 512);
    bA0[0] = ldnt(A0);
    bA0[1] = ldnt(A0 + 4);
    bA0[2] = ldnt(A1);
    bA0[3] = ldnt(A1 + 4);

    for (int ks = 0; ks < 16; ks += 2) {
        // prefetch odd step (ks+1) into set 1  (ks+1 <= 15 always)
        {
            const _Float16* Bn = Bp + (size_t)(ks + 1) * NTILE * 512;
            #pragma unroll
            for (int nt = 0; nt < NTILE; nt++)
                bB1[nt] = *(const half8*)(Bn + nt * 512);
            const float* a0 = A0 + (ks + 1) * 32;
            const float* a1 = A1 + (ks + 1) * 32;
            bA1[0] = ldnt(a0);
            bA1[1] = ldnt(a0 + 4);
            bA1[2] = ldnt(a1);
            bA1[3] = ldnt(a1 + 4);
        }
        // compute even step from set 0
        {
            const half8 af0 = pack_af(bA0[0], bA0[1]);
            const half8 af1 = pack_af(bA0[2], bA0[3]);
            #pragma unroll
            for (int nt = 0; nt < NTILE; nt++) {
                acc0[nt] = __builtin_amdgcn_mfma_f32_16x16x32_f16(af0, bB0[nt], acc0[nt], 0, 0, 0);
                acc1[nt] = __builtin_amdgcn_mfma_f32_16x16x32_f16(af1, bB0[nt], acc1[nt], 0, 0, 0);
            }
        }
        // prefetch next even step (ks+2) into set 0
        if (ks < 14) {
            const _Float16* Bn = Bp + (size_t)(ks + 2) * NTILE * 512;
            #pragma unroll
            for (int nt = 0; nt < NTILE; nt++)
                bB0[nt] = *(const half8*)(Bn + nt * 512);
            const float* a0 = A0 + (ks + 2) * 32;
            const float* a1 = A1 + (ks + 2) * 32;
            bA0[0] = ldnt(a0);
            bA0[1] = ldnt(a0 + 4);
            bA0[2] = ldnt(a1);
            bA0[3] = ldnt(a1 + 4);
        }
        // compute odd step from set 1
        {
            const half8 af0 = pack_af(bA1[0], bA1[1]);
            const half8 af1 = pack_af(bA1[2], bA1[3]);
            #pragma unroll
            for (int nt = 0; nt < NTILE; nt++) {
                acc0[nt] = __builtin_amdgcn_mfma_f32_16x16x32_f16(af0, bB1[nt], acc0[nt], 0, 0, 0);
                acc1[nt] = __builtin_amdgcn_mfma_f32_16x16x32_f16(af1, bB1[nt], acc1[nt], 0, 0, 0);
            }
        }
    }

    // C/D layout (measured m89/m91): col = lane&15, row = quad*4 + reg.
    #pragma unroll
    for (int nt = 0; nt < NTILE; nt++) {
        #pragma unroll
        for (int r = 0; r < 4; r++) {
            red[wave][quad * 4 + r][nt * 16 + low]      = acc0[nt][r];
            red[wave][16 + quad * 4 + r][nt * 16 + low] = acc1[nt][r];
        }
    }
    __syncthreads();

    // Epilogue: thread -> (row = tid>>3 in [0,32), top = tid&7). All active.
    const int row = tid >> 3;
    const int top = tid & 7;
    {
        float zt = top_b[top];
        #pragma unroll
        for (int w = 0; w < 4; w++) zt += red[w][row][top];
        const float sig = 1.0f / (1.0f + __expf(-zt));

        float z[16];
        float zmax = -1e30f;
        #pragma unroll
        for (int c = 0; c < 16; c++) {
            float v = bot_b[top * 16 + c];
            #pragma unroll
            for (int w = 0; w < 4; w++) v += red[w][row][8 + top * 16 + c];
            z[c] = v;
            zmax = fmaxf(zmax, v);
        }
        float s = 0.0f;
        #pragma unroll
        for (int c = 0; c < 16; c++) { z[c] = __expf(z[c] - zmax); s += z[c]; }
        const float scale = sig / s;

        float* o = out + (row0 + row) * 128 + top * 16;
        #pragma unroll
        for (int c = 0; c < 16; c += 4) {
            f32x4 v = { z[c] * scale, z[c+1] * scale, z[c+2] * scale, z[c+3] * scale };
            __builtin_nontemporal_store(v, (f32x4*)(o + c));
        }
    }
}

extern "C" void kernel_launch(void* const* d_in, const int* in_sizes, int n_in,
                              void* d_out, int out_size, void* d_ws, size_t ws_size,
                              hipStream_t stream) {
    const float* feat  = (const float*)d_in[0];   // (16384, 2048)
    const float* topW  = (const float*)d_in[1];   // (8, 2048)
    const float* topB  = (const float*)d_in[2];   // (8,)
    const float* botW  = (const float*)d_in[3];   // (8, 2048, 16)
    const float* botB  = (const float*)d_in[4];   // (8, 16)
    float* out = (float*)d_out;                   // (16384, 128)
    _Float16* Bsw = (_Float16*)d_ws;              // 144*2048 fp16 = 576 KB swizzled

    prep_weights<<<(4 * 16 * NTILE * 64 + 255) / 256, 256, 0, stream>>>(topW, botW, Bsw);
    hc_fused<<<16384 / M_ROWS, 256, 0, stream>>>(feat, Bsw, topB, botB, out);
}